// Round 1
// baseline (224.166 us; speedup 1.0000x reference)
//
#include <hip/hip_runtime.h>
#include <hip/hip_bf16.h>

// ChunkAggregator: B=4, L=8192, V=32000, D=1024, block=128, nb=64.
// Outputs (flat f32, concatenated in return order):
//   [0]               new_tokens : B x (nb+L) = 4 x 8256   = 33024
//   [33024]           cat_emb    : B x nb x D = 4x64x1024  = 262144
//   [33024+262144]    hist       : B x nb x V = 4x64x32000 = 8192000
// Strategy: one block per (b,n,v-split). Zero-fill hist slice with float4,
// then scatter duplicate counts (first-occurrence thread writes, no atomics).

namespace {
constexpr int B   = 4;
constexpr int L   = 8192;
constexpr int V   = 32000;
constexpr int D   = 1024;
constexpr int BLK = 128;           // token block size
constexpr int NB  = L / BLK;       // 64
constexpr int SPLIT  = 4;          // v-range splits per (b,n)
constexpr int VCHUNK = V / SPLIT;  // 8000
constexpr int NT_LEN = NB + L;     // 8256
constexpr size_t OFF_CAT  = (size_t)B * NT_LEN;           // 33024
constexpr size_t OFF_HIST = OFF_CAT + (size_t)B * NB * D; // 295168
}

__global__ __launch_bounds__(256) void chunk_agg_kernel(
    const int* __restrict__ tokens,
    const float* __restrict__ catW,
    float* __restrict__ out) {
  const int bid   = blockIdx.x;          // [0, B*NB*SPLIT)
  const int split = bid & (SPLIT - 1);
  const int bn    = bid >> 2;            // [0, B*NB)
  const int b     = bn >> 6;             // / NB
  const int n     = bn & (NB - 1);
  const int t     = threadIdx.x;         // 256 threads

  __shared__ int stok[BLK];
  const int* tok = tokens + (size_t)b * L + (size_t)n * BLK;
  if (t < BLK) stok[t] = tok[t];

  // ---- zero-fill this block's hist slice (8000 floats -> 2000 float4) ----
  float* hist = out + OFF_HIST + (size_t)bn * V + (size_t)split * VCHUNK;
  float4* h4 = reinterpret_cast<float4*>(hist);
  const float4 z = make_float4(0.f, 0.f, 0.f, 0.f);
  #pragma unroll
  for (int i = t; i < VCHUNK / 4; i += 256) h4[i] = z;

  __syncthreads();

  // ---- scatter counts: thread t owns token t; first occurrence writes ----
  if (t < BLK) {
    const int v = stok[t];
    const int lo = split * VCHUNK;
    if (v >= lo && v < lo + VCHUNK) {
      int cnt = 0;
      bool first = true;
      #pragma unroll 8
      for (int j = 0; j < BLK; ++j) {
        const int vj = stok[j];
        cnt += (vj == v) ? 1 : 0;
        if (vj == v && j < t) first = false;
      }
      if (first) hist[v - lo] = (float)cnt;
    }
  }

  // ---- split 0 also handles cat_emb row + new_tokens chunk ----
  if (split == 0) {
    const int tok0 = stok[0];
    const float4* src = reinterpret_cast<const float4*>(catW + (size_t)tok0 * D);
    float4* dst = reinterpret_cast<float4*>(out + OFF_CAT + (size_t)bn * D);
    #pragma unroll
    for (int i = t; i < D / 4; i += 256) dst[i] = src[i];

    float* nt = out + (size_t)b * NT_LEN;
    if (t == 0) nt[n] = (float)tok0;                    // cat_dummy part
    if (t < BLK) nt[NB + n * BLK + t] = (float)stok[t]; // tokens part
  }
}

extern "C" void kernel_launch(void* const* d_in, const int* in_sizes, int n_in,
                              void* d_out, int out_size, void* d_ws, size_t ws_size,
                              hipStream_t stream) {
  const int*   tokens = (const int*)d_in[0];
  const float* catW   = (const float*)d_in[1];
  // d_in[2] (num_embed_W) is only used in dead code in the reference.
  float* out = (float*)d_out;

  const int grid = B * NB * SPLIT;  // 1024 blocks
  chunk_agg_kernel<<<grid, 256, 0, stream>>>(tokens, catW, out);
}